// Round 2
// baseline (425.372 us; speedup 1.0000x reference)
//
#include <hip/hip_runtime.h>
#include <math.h>

#define N_NODES 50000
#define N_EDGES 800000
#define D_IN    256
#define D_HID   128
#define D_OUT   64

// ---------------- edge dtype detection ----------------
// Reference edge_index is int64; harness may deliver int32 or raw int64.
// If int64: high word of every value (<50000) is 0 -> odd int32s all zero.
// If int32: odd elements are random node ids. Flag: 1 => int32, 0 => int64.

__global__ void k_detect(const void* __restrict__ ei, int* __restrict__ flag) {
    int t = threadIdx.x;                     // 256 threads
    int v = ((const int*)ei)[2 * t + 1];
    if (v != 0) atomicOr(flag, 1);
}

__device__ __forceinline__ int edge_at(const void* ei, int is64, int which, int i) {
    if (is64) return (int)((const long long*)ei)[(size_t)which * N_EDGES + i];
    return ((const int*)ei)[which * N_EDGES + i];
}

// ---------------- degree / CSR build ----------------

__global__ void k_count(const void* __restrict__ ei, const int* __restrict__ flag,
                        int* __restrict__ cnt) {
    int i = blockIdx.x * blockDim.x + threadIdx.x;
    int is64 = (flag[0] == 0);
    if (i < N_EDGES) atomicAdd(&cnt[edge_at(ei, is64, 1, i)], 1);
}

__global__ void k_dinv(const int* __restrict__ cnt, float* __restrict__ dinv) {
    int i = blockIdx.x * blockDim.x + threadIdx.x;
    if (i < N_NODES) dinv[i] = rsqrtf(1.0f + (float)cnt[i]);
}

#define SCAN_B 256
__global__ void k_scan1(const int* __restrict__ cnt, int* __restrict__ ex,
                        int* __restrict__ partials, int n) {
    __shared__ int sm[SCAN_B];
    int t = threadIdx.x;
    int i = blockIdx.x * SCAN_B + t;
    int v = (i < n) ? cnt[i] : 0;
    sm[t] = v; __syncthreads();
    for (int off = 1; off < SCAN_B; off <<= 1) {
        int add = (t >= off) ? sm[t - off] : 0;
        __syncthreads();
        sm[t] += add;
        __syncthreads();
    }
    if (i < n) ex[i] = sm[t] - v;          // exclusive
    if (t == SCAN_B - 1) partials[blockIdx.x] = sm[t];
}

__global__ void k_scan2(int* __restrict__ partials, int nb) {
    __shared__ int sm[SCAN_B];
    int t = threadIdx.x;
    int v = (t < nb) ? partials[t] : 0;
    sm[t] = v; __syncthreads();
    for (int off = 1; off < SCAN_B; off <<= 1) {
        int add = (t >= off) ? sm[t - off] : 0;
        __syncthreads();
        sm[t] += add;
        __syncthreads();
    }
    if (t < nb) partials[t] = sm[t] - v;   // exclusive block offsets
}

__global__ void k_scan3(int* __restrict__ ex, const int* __restrict__ partials, int n) {
    int i = blockIdx.x * SCAN_B + threadIdx.x;
    if (i < n) ex[i] += partials[blockIdx.x];
}

__global__ void k_fill(const void* __restrict__ ei, const int* __restrict__ flag,
                       const int* __restrict__ rowstart, int* __restrict__ cursor,
                       int* __restrict__ colidx) {
    int i = blockIdx.x * blockDim.x + threadIdx.x;
    int is64 = (flag[0] == 0);
    if (i < N_EDGES) {
        int s = edge_at(ei, is64, 0, i);
        int d = edge_at(ei, is64, 1, i);
        int pos = rowstart[d] + atomicAdd(&cursor[d], 1);
        colidx[pos] = s;
    }
}

// ---------------- GEMM: C[M,NF] = A[M,K] @ W[K,NF], f32 ----------------

template <int K, int NF, int MT, int KT>
__global__ void k_gemm(const float* __restrict__ A, const float* __restrict__ W,
                       float* __restrict__ C, int M) {
    constexpr int TFX = NF / 4;                 // threads along f
    constexpr int NTHREADS = TFX * (MT / 4);    // must be 256
    __shared__ float wl[KT][NF];
    __shared__ float xl[KT][MT];

    const int t = threadIdx.x;
    const int m0 = blockIdx.x * MT;
    const int f0 = (t % TFX) * 4;
    const int n0 = (t / TFX) * 4;

    float acc[4][4] = {};

    for (int k0 = 0; k0 < K; k0 += KT) {
        // stage W chunk
        constexpr int WLOADS = KT * NF / 4;
        for (int idx = t; idx < WLOADS; idx += NTHREADS) {
            int kk = idx / (NF / 4);
            int ff = (idx % (NF / 4)) * 4;
            *(float4*)&wl[kk][ff] = *(const float4*)&W[(k0 + kk) * NF + ff];
        }
        // stage A chunk transposed
        constexpr int XLOADS = MT * KT / 4;
        for (int idx = t; idx < XLOADS; idx += NTHREADS) {
            int n  = idx / (KT / 4);
            int kc = (idx % (KT / 4)) * 4;
            float4 xv = make_float4(0.f, 0.f, 0.f, 0.f);
            int row = m0 + n;
            if (row < M) xv = *(const float4*)&A[row * K + k0 + kc];
            xl[kc + 0][n] = xv.x; xl[kc + 1][n] = xv.y;
            xl[kc + 2][n] = xv.z; xl[kc + 3][n] = xv.w;
        }
        __syncthreads();
        for (int kk = 0; kk < KT; ++kk) {
            float4 wv = *(const float4*)&wl[kk][f0];
            float4 xv = *(const float4*)&xl[kk][n0];
            acc[0][0] += xv.x * wv.x; acc[0][1] += xv.x * wv.y; acc[0][2] += xv.x * wv.z; acc[0][3] += xv.x * wv.w;
            acc[1][0] += xv.y * wv.x; acc[1][1] += xv.y * wv.y; acc[1][2] += xv.y * wv.z; acc[1][3] += xv.y * wv.w;
            acc[2][0] += xv.z * wv.x; acc[2][1] += xv.z * wv.y; acc[2][2] += xv.z * wv.z; acc[2][3] += xv.z * wv.w;
            acc[3][0] += xv.w * wv.x; acc[3][1] += xv.w * wv.y; acc[3][2] += xv.w * wv.z; acc[3][3] += xv.w * wv.w;
        }
        __syncthreads();
    }

    for (int i = 0; i < 4; ++i) {
        int row = m0 + n0 + i;
        if (row < M) {
            float4 o = make_float4(acc[i][0], acc[i][1], acc[i][2], acc[i][3]);
            *(float4*)&C[row * NF + f0] = o;
        }
    }
}

// ---------------- fused aggregate + bias (+relu) + sigmoid gate ----------------

// layer 1: NF=128, relu=yes. One block of 128 threads per node.
__global__ void k_agg1(const float* __restrict__ h, const int* __restrict__ rowstart,
                       const int* __restrict__ cnt, const int* __restrict__ colidx,
                       const float* __restrict__ dinv,
                       const float* __restrict__ b, const float* __restrict__ aw,
                       const float* __restrict__ ab, float* __restrict__ out) {
    int v = blockIdx.x;
    int f = threadIdx.x;
    float dv = dinv[v];
    float acc = h[v * D_HID + f] * dv * dv;
    int start = rowstart[v], len = cnt[v];
    for (int j = 0; j < len; ++j) {
        int s = colidx[start + j];
        acc += h[s * D_HID + f] * (dinv[s] * dv);
    }
    acc += b[f];
    acc = fmaxf(acc, 0.0f);
    float p = acc * aw[f];
    for (int off = 32; off > 0; off >>= 1) p += __shfl_down(p, off);
    __shared__ float red[2];
    if ((f & 63) == 0) red[f >> 6] = p;
    __syncthreads();
    float dot = red[0] + red[1] + ab[0];
    float g = 1.0f / (1.0f + expf(-dot));
    out[v * D_HID + f] = acc * g;
}

// layer 2: NF=64, no relu. One wave per node.
__global__ void k_agg2(const float* __restrict__ h, const int* __restrict__ rowstart,
                       const int* __restrict__ cnt, const int* __restrict__ colidx,
                       const float* __restrict__ dinv,
                       const float* __restrict__ b, const float* __restrict__ aw,
                       const float* __restrict__ ab, float* __restrict__ out) {
    int v = blockIdx.x;
    int f = threadIdx.x;
    float dv = dinv[v];
    float acc = h[v * D_OUT + f] * dv * dv;
    int start = rowstart[v], len = cnt[v];
    for (int j = 0; j < len; ++j) {
        int s = colidx[start + j];
        acc += h[s * D_OUT + f] * (dinv[s] * dv);
    }
    acc += b[f];
    float p = acc * aw[f];
    for (int off = 32; off > 0; off >>= 1) p += __shfl_down(p, off);
    float dot = __shfl(p, 0) + ab[0];
    float g = 1.0f / (1.0f + expf(-dot));
    out[v * D_OUT + f] = acc * g;
}

// ---------------- launch ----------------

static inline size_t align_up(size_t x, size_t a) { return (x + a - 1) & ~(a - 1); }

extern "C" void kernel_launch(void* const* d_in, const int* in_sizes, int n_in,
                              void* d_out, int out_size, void* d_ws, size_t ws_size,
                              hipStream_t stream) {
    const float* x   = (const float*)d_in[0];
    const void*  ei  = d_in[1];
    const float* W1  = (const float*)d_in[2];
    const float* b1  = (const float*)d_in[3];
    const float* W2  = (const float*)d_in[4];
    const float* b2  = (const float*)d_in[5];
    const float* aw1 = (const float*)d_in[6];
    const float* ab1 = (const float*)d_in[7];
    const float* aw2 = (const float*)d_in[8];
    const float* ab2 = (const float*)d_in[9];
    float* out = (float*)d_out;

    // workspace layout
    char* w = (char*)d_ws;
    size_t off = 0;
    int*   flag     = (int*)(w + off); off = align_up(off + 4, 256);
    int*   cnt      = (int*)(w + off); off = align_up(off + N_NODES * 4, 256);
    int*   rowstart = (int*)(w + off); off = align_up(off + N_NODES * 4, 256);
    int*   cursor   = (int*)(w + off); off = align_up(off + N_NODES * 4, 256);
    int*   partials = (int*)(w + off); off = align_up(off + 1024 * 4, 256);
    float* dinv     = (float*)(w + off); off = align_up(off + N_NODES * 4, 256);
    int*   colidx   = (int*)(w + off); off = align_up(off + (size_t)N_EDGES * 4, 256);
    float* h1g      = (float*)(w + off); off = align_up(off + (size_t)N_NODES * D_HID * 4, 256);
    float* h1       = (float*)(w + off); // h2 overlays h1 (h1 dead after k_agg1)
    float* h2       = h1;
    off = align_up(off + (size_t)N_NODES * D_HID * 4, 256);
    (void)ws_size; (void)out_size; (void)n_in; (void)in_sizes;

    hipMemsetAsync(flag, 0, 4, stream);
    hipMemsetAsync(cnt, 0, N_NODES * 4, stream);
    hipMemsetAsync(cursor, 0, N_NODES * 4, stream);

    const int eb = (N_EDGES + 255) / 256;
    const int nb = (N_NODES + 255) / 256;
    const int sb = (N_NODES + SCAN_B - 1) / SCAN_B;   // 196

    k_detect<<<1, 256, 0, stream>>>(ei, flag);
    k_count<<<eb, 256, 0, stream>>>(ei, flag, cnt);
    k_dinv<<<nb, 256, 0, stream>>>(cnt, dinv);
    k_scan1<<<sb, SCAN_B, 0, stream>>>(cnt, rowstart, partials, N_NODES);
    k_scan2<<<1, SCAN_B, 0, stream>>>(partials, sb);
    k_scan3<<<sb, SCAN_B, 0, stream>>>(rowstart, partials, N_NODES);
    k_fill<<<eb, 256, 0, stream>>>(ei, flag, rowstart, cursor, colidx);

    // layer 1: h1 = x @ W1
    k_gemm<D_IN, D_HID, 32, 64><<<(N_NODES + 31) / 32, 256, 0, stream>>>(x, W1, h1, N_NODES);
    k_agg1<<<N_NODES, D_HID, 0, stream>>>(h1, rowstart, cnt, colidx, dinv, b1, aw1, ab1, h1g);

    // layer 2: h2 = h1g @ W2
    k_gemm<D_HID, D_OUT, 64, 64><<<(N_NODES + 63) / 64, 256, 0, stream>>>(h1g, W2, h2, N_NODES);
    k_agg2<<<N_NODES, D_OUT, 0, stream>>>(h2, rowstart, cnt, colidx, dinv, b2, aw2, ab2, out);
}

// Round 3
// 329.389 us; speedup vs baseline: 1.2914x; 1.2914x over previous
//
#include <hip/hip_runtime.h>
#include <math.h>

#define N_NODES 50000
#define N_EDGES 800000
#define D_IN    256
#define D_HID   128
#define D_OUT   64

typedef unsigned int u32;

__device__ __forceinline__ float bflo(u32 u) {
    union { u32 i; float f; } c; c.i = u << 16; return c.f;
}
__device__ __forceinline__ float bfhi(u32 u) {
    union { u32 i; float f; } c; c.i = u & 0xffff0000u; return c.f;
}
__device__ __forceinline__ u32 pack_bf2(float a, float b) {
    union { float f; u32 i; } ca, cb; ca.f = a; cb.f = b;
    u32 ra = (ca.i + 0x7fffu + ((ca.i >> 16) & 1u)) >> 16;
    u32 rb = (cb.i + 0x7fffu + ((cb.i >> 16) & 1u)) & 0xffff0000u;
    return ra | rb;
}

// ---------------- edge dtype detection ----------------
__global__ void k_detect(const void* __restrict__ ei, int* __restrict__ flag) {
    int t = threadIdx.x;
    int v = ((const int*)ei)[2 * t + 1];
    if (v != 0) atomicOr(flag, 1);
}

__device__ __forceinline__ int edge_at(const void* ei, int is64, int which, int i) {
    if (is64) return (int)((const long long*)ei)[(size_t)which * N_EDGES + i];
    return ((const int*)ei)[which * N_EDGES + i];
}

// ---------------- degree / CSR build ----------------

__global__ void k_count(const void* __restrict__ ei, const int* __restrict__ flag,
                        int* __restrict__ cnt) {
    int i = blockIdx.x * blockDim.x + threadIdx.x;
    int is64 = (flag[0] == 0);
    if (i < N_EDGES) atomicAdd(&cnt[edge_at(ei, is64, 1, i)], 1);
}

__global__ void k_dinv(const int* __restrict__ cnt, float* __restrict__ dinv) {
    int i = blockIdx.x * blockDim.x + threadIdx.x;
    if (i < N_NODES) dinv[i] = rsqrtf(1.0f + (float)cnt[i]);
}

#define SCAN_B 256
__global__ void k_scan1(const int* __restrict__ cnt, int* __restrict__ ex,
                        int* __restrict__ partials, int n) {
    __shared__ int sm[SCAN_B];
    int t = threadIdx.x;
    int i = blockIdx.x * SCAN_B + t;
    int v = (i < n) ? cnt[i] : 0;
    sm[t] = v; __syncthreads();
    for (int off = 1; off < SCAN_B; off <<= 1) {
        int add = (t >= off) ? sm[t - off] : 0;
        __syncthreads();
        sm[t] += add;
        __syncthreads();
    }
    if (i < n) ex[i] = sm[t] - v;
    if (t == SCAN_B - 1) partials[blockIdx.x] = sm[t];
}

__global__ void k_scan2(int* __restrict__ partials, int nb) {
    __shared__ int sm[SCAN_B];
    int t = threadIdx.x;
    int v = (t < nb) ? partials[t] : 0;
    sm[t] = v; __syncthreads();
    for (int off = 1; off < SCAN_B; off <<= 1) {
        int add = (t >= off) ? sm[t - off] : 0;
        __syncthreads();
        sm[t] += add;
        __syncthreads();
    }
    if (t < nb) partials[t] = sm[t] - v;
}

__global__ void k_scan3(int* __restrict__ ex, const int* __restrict__ partials, int n) {
    int i = blockIdx.x * SCAN_B + threadIdx.x;
    if (i < n) ex[i] += partials[blockIdx.x];
}

__global__ void k_fill(const void* __restrict__ ei, const int* __restrict__ flag,
                       const int* __restrict__ rowstart, int* __restrict__ cursor,
                       int* __restrict__ colidx) {
    int i = blockIdx.x * blockDim.x + threadIdx.x;
    int is64 = (flag[0] == 0);
    if (i < N_EDGES) {
        int s = edge_at(ei, is64, 0, i);
        int d = edge_at(ei, is64, 1, i);
        int pos = rowstart[d] + atomicAdd(&cursor[d], 1);
        colidx[pos] = s;
    }
}

// ---- GEMM: Cp[r, :] = pack_bf16( (A[r,:] @ W) * dinv[r] ), f32 math ----

template <int K, int NF, int MT, int KT>
__global__ void k_gemm_s(const float* __restrict__ A, const float* __restrict__ W,
                         const float* __restrict__ dinv, u32* __restrict__ Cp, int M) {
    constexpr int TFX = NF / 4;
    constexpr int NTHREADS = TFX * (MT / 4);    // must be 256
    __shared__ float wl[KT][NF];
    __shared__ float xl[KT][MT];

    const int t = threadIdx.x;
    const int m0 = blockIdx.x * MT;
    const int f0 = (t % TFX) * 4;
    const int n0 = (t / TFX) * 4;

    float acc[4][4] = {};

    for (int k0 = 0; k0 < K; k0 += KT) {
        constexpr int WLOADS = KT * NF / 4;
        for (int idx = t; idx < WLOADS; idx += NTHREADS) {
            int kk = idx / (NF / 4);
            int ff = (idx % (NF / 4)) * 4;
            *(float4*)&wl[kk][ff] = *(const float4*)&W[(k0 + kk) * NF + ff];
        }
        // stage A transposed; n varies fastest across lanes -> conflict-free LDS stores
        constexpr int XLOADS = MT * KT / 4;
        for (int idx = t; idx < XLOADS; idx += NTHREADS) {
            int n  = idx % MT;
            int kc = (idx / MT) * 4;
            float4 xv = make_float4(0.f, 0.f, 0.f, 0.f);
            int row = m0 + n;
            if (row < M) xv = *(const float4*)&A[row * K + k0 + kc];
            xl[kc + 0][n] = xv.x; xl[kc + 1][n] = xv.y;
            xl[kc + 2][n] = xv.z; xl[kc + 3][n] = xv.w;
        }
        __syncthreads();
        for (int kk = 0; kk < KT; ++kk) {
            float4 wv = *(const float4*)&wl[kk][f0];
            float4 xv = *(const float4*)&xl[kk][n0];
            acc[0][0] += xv.x * wv.x; acc[0][1] += xv.x * wv.y; acc[0][2] += xv.x * wv.z; acc[0][3] += xv.x * wv.w;
            acc[1][0] += xv.y * wv.x; acc[1][1] += xv.y * wv.y; acc[1][2] += xv.y * wv.z; acc[1][3] += xv.y * wv.w;
            acc[2][0] += xv.z * wv.x; acc[2][1] += xv.z * wv.y; acc[2][2] += xv.z * wv.z; acc[2][3] += xv.z * wv.w;
            acc[3][0] += xv.w * wv.x; acc[3][1] += xv.w * wv.y; acc[3][2] += xv.w * wv.z; acc[3][3] += xv.w * wv.w;
        }
        __syncthreads();
    }

    for (int i = 0; i < 4; ++i) {
        int row = m0 + n0 + i;
        if (row < M) {
            float s = dinv[row];
            uint2 o;
            o.x = pack_bf2(acc[i][0] * s, acc[i][1] * s);
            o.y = pack_bf2(acc[i][2] * s, acc[i][3] * s);
            *(uint2*)&Cp[(size_t)row * (NF / 2) + f0 / 2] = o;
        }
    }
}

// ---------------- fused aggregate + bias (+relu) + sigmoid gate ----------------
// hs rows are pre-scaled by dinv[row]; agg = dv * (hs[v] + sum hs[neighbor]).

// layer 1: 128 feats = 64 u32/row. One wave per node; lane l = feats (2l, 2l+1).
__global__ void k_agg1(const u32* __restrict__ hs, const int* __restrict__ rowstart,
                       const int* __restrict__ cnt, const int* __restrict__ colidx,
                       const float* __restrict__ dinv,
                       const float* __restrict__ b, const float* __restrict__ aw,
                       const float* __restrict__ ab, float* __restrict__ out) {
    int v = blockIdx.x;
    int l = threadIdx.x;
    float dv = dinv[v];
    u32 su = hs[(size_t)v * 64 + l];
    float ax = bflo(su), ay = bfhi(su);
    int start = rowstart[v], len = cnt[v];
    const int* cx = colidx + start;
    int j = 0;
    for (; j + 4 <= len; j += 4) {
        int s0 = cx[j], s1 = cx[j + 1], s2 = cx[j + 2], s3 = cx[j + 3];
        u32 u0 = hs[(size_t)s0 * 64 + l];
        u32 u1 = hs[(size_t)s1 * 64 + l];
        u32 u2 = hs[(size_t)s2 * 64 + l];
        u32 u3 = hs[(size_t)s3 * 64 + l];
        ax += bflo(u0) + bflo(u1) + bflo(u2) + bflo(u3);
        ay += bfhi(u0) + bfhi(u1) + bfhi(u2) + bfhi(u3);
    }
    for (; j < len; ++j) {
        u32 u = hs[(size_t)cx[j] * 64 + l];
        ax += bflo(u); ay += bfhi(u);
    }
    float2 bp = ((const float2*)b)[l];
    ax = fmaxf(ax * dv + bp.x, 0.0f);
    ay = fmaxf(ay * dv + bp.y, 0.0f);
    float2 ap = ((const float2*)aw)[l];
    float p = ax * ap.x + ay * ap.y;
    for (int off = 32; off; off >>= 1) p += __shfl_xor(p, off);
    float g = 1.0f / (1.0f + expf(-(p + ab[0])));
    ((float2*)out)[(size_t)v * 64 + l] = make_float2(ax * g, ay * g);
}

// layer 2: 64 feats = 32 u32/row. One wave per node, split into 2 half-waves
// that process alternating neighbors (2 rows in flight, x2 unroll = 4).
__global__ void k_agg2(const u32* __restrict__ hs, const int* __restrict__ rowstart,
                       const int* __restrict__ cnt, const int* __restrict__ colidx,
                       const float* __restrict__ dinv,
                       const float* __restrict__ b, const float* __restrict__ aw,
                       const float* __restrict__ ab, float* __restrict__ out) {
    int v = blockIdx.x;
    int l = threadIdx.x;
    int c = l & 31, half = l >> 5;
    float dv = dinv[v];
    float ax = 0.0f, ay = 0.0f;
    if (half == 0) {
        u32 su = hs[(size_t)v * 32 + c];
        ax = bflo(su); ay = bfhi(su);
    }
    int start = rowstart[v], len = cnt[v];
    const int* cx = colidx + start;
    int j = half;
    for (; j + 2 < len; j += 4) {
        int s0 = cx[j], s1 = cx[j + 2];
        u32 u0 = hs[(size_t)s0 * 32 + c];
        u32 u1 = hs[(size_t)s1 * 32 + c];
        ax += bflo(u0) + bflo(u1);
        ay += bfhi(u0) + bfhi(u1);
    }
    if (j < len) {
        u32 u = hs[(size_t)cx[j] * 32 + c];
        ax += bflo(u); ay += bfhi(u);
    }
    ax += __shfl_xor(ax, 32);
    ay += __shfl_xor(ay, 32);
    float2 bp = ((const float2*)b)[c];
    ax = ax * dv + bp.x;
    ay = ay * dv + bp.y;
    float2 ap = ((const float2*)aw)[c];
    float p = ax * ap.x + ay * ap.y;
    for (int off = 16; off; off >>= 1) p += __shfl_xor(p, off);
    float g = 1.0f / (1.0f + expf(-(p + ab[0])));
    if (half == 0) ((float2*)out)[(size_t)v * 32 + c] = make_float2(ax * g, ay * g);
}

// ---------------- launch ----------------

static inline size_t align_up(size_t x, size_t a) { return (x + a - 1) & ~(a - 1); }

extern "C" void kernel_launch(void* const* d_in, const int* in_sizes, int n_in,
                              void* d_out, int out_size, void* d_ws, size_t ws_size,
                              hipStream_t stream) {
    const float* x   = (const float*)d_in[0];
    const void*  ei  = d_in[1];
    const float* W1  = (const float*)d_in[2];
    const float* b1  = (const float*)d_in[3];
    const float* W2  = (const float*)d_in[4];
    const float* b2  = (const float*)d_in[5];
    const float* aw1 = (const float*)d_in[6];
    const float* ab1 = (const float*)d_in[7];
    const float* aw2 = (const float*)d_in[8];
    const float* ab2 = (const float*)d_in[9];
    float* out = (float*)d_out;

    char* w = (char*)d_ws;
    size_t off = 0;
    int*   flag     = (int*)(w + off); off = align_up(off + 4, 256);
    int*   cnt      = (int*)(w + off); off = align_up(off + N_NODES * 4, 256);
    int*   rowstart = (int*)(w + off); off = align_up(off + N_NODES * 4, 256);
    int*   cursor   = (int*)(w + off); off = align_up(off + N_NODES * 4, 256);
    int*   partials = (int*)(w + off); off = align_up(off + 1024 * 4, 256);
    float* dinv     = (float*)(w + off); off = align_up(off + N_NODES * 4, 256);
    int*   colidx   = (int*)(w + off); off = align_up(off + (size_t)N_EDGES * 4, 256);
    u32*   h1s      = (u32*)(w + off); off = align_up(off + (size_t)N_NODES * 64 * 4, 256);
    float* h1g      = (float*)(w + off); off = align_up(off + (size_t)N_NODES * D_HID * 4, 256);
    u32*   h2s      = (u32*)(w + off); off = align_up(off + (size_t)N_NODES * 32 * 4, 256);
    (void)ws_size; (void)out_size; (void)n_in; (void)in_sizes;

    hipMemsetAsync(flag, 0, 4, stream);
    hipMemsetAsync(cnt, 0, N_NODES * 4, stream);
    hipMemsetAsync(cursor, 0, N_NODES * 4, stream);

    const int eb = (N_EDGES + 255) / 256;
    const int nb = (N_NODES + 255) / 256;
    const int sb = (N_NODES + SCAN_B - 1) / SCAN_B;

    k_detect<<<1, 256, 0, stream>>>(ei, flag);
    k_count<<<eb, 256, 0, stream>>>(ei, flag, cnt);
    k_dinv<<<nb, 256, 0, stream>>>(cnt, dinv);
    k_scan1<<<sb, SCAN_B, 0, stream>>>(cnt, rowstart, partials, N_NODES);
    k_scan2<<<1, SCAN_B, 0, stream>>>(partials, sb);
    k_scan3<<<sb, SCAN_B, 0, stream>>>(rowstart, partials, N_NODES);
    k_fill<<<eb, 256, 0, stream>>>(ei, flag, rowstart, cursor, colidx);

    // layer 1: h1s = pack_bf16((x @ W1) * dinv)
    k_gemm_s<D_IN, D_HID, 32, 64><<<(N_NODES + 31) / 32, 256, 0, stream>>>(x, W1, dinv, h1s, N_NODES);
    k_agg1<<<N_NODES, 64, 0, stream>>>(h1s, rowstart, cnt, colidx, dinv, b1, aw1, ab1, h1g);

    // layer 2: h2s = pack_bf16((h1g @ W2) * dinv)
    k_gemm_s<D_HID, D_OUT, 64, 64><<<(N_NODES + 63) / 64, 256, 0, stream>>>(h1g, W2, dinv, h2s, N_NODES);
    k_agg2<<<N_NODES, 64, 0, stream>>>(h2s, rowstart, cnt, colidx, dinv, b2, aw2, ab2, out);
}